// Round 11
// baseline (146.958 us; speedup 1.0000x reference)
//
#include <hip/hip_runtime.h>
#include <math.h>

typedef __attribute__((ext_vector_type(4))) float f32x4;
typedef __attribute__((ext_vector_type(8))) short s16x8;

constexpr int B_ = 8, C_ = 384, N_ = 1024, NH_ = 8, D_ = 48;
constexpr float SCALE_ = 0.14433756729740643f; // 1/sqrt(48)

__device__ __forceinline__ unsigned short f2bf(float f) {
    unsigned u = __builtin_bit_cast(unsigned, f);
    u += 0x7fff + ((u >> 16) & 1);           // round-to-nearest-even
    return (unsigned short)(u >> 16);
}
__device__ __forceinline__ unsigned short f2bf_trunc(float f) {
    return (unsigned short)(__builtin_bit_cast(unsigned, f) >> 16);
}

// ---------------------------------------------------------------------------
// Kernel 1: LayerNorm (float4 loads, LDS transpose, int4 stores) + weight cvt.
// ---------------------------------------------------------------------------
__global__ __launch_bounds__(256) void ln_cvt_kernel(const float* __restrict__ x,
                                                     const float* __restrict__ lnw,
                                                     const float* __restrict__ lnb,
                                                     const float* __restrict__ wq,
                                                     const float* __restrict__ wp,
                                                     unsigned short* __restrict__ t,
                                                     unsigned short* __restrict__ wqb,
                                                     unsigned short* __restrict__ wpb) {
    int tid = threadIdx.x;
    int gid = blockIdx.x * 256 + tid;
    for (int i = gid; i < 1152 * 384; i += 512 * 256) wqb[i] = f2bf(wq[i]);
    for (int i = gid; i < 384 * 384;  i += 512 * 256) wpb[i] = f2bf(wp[i]);

    __shared__ float xs[384][17];
    __shared__ float wgt[384], bia[384];
    int b  = blockIdx.x >> 6;
    int n0 = (blockIdx.x & 63) << 4;
    for (int i = tid; i < 384; i += 256) { wgt[i] = lnw[i]; bia[i] = lnb[i]; }

    const float* xb = x + (size_t)b * 384 * 1024;
    #pragma unroll
    for (int k = 0; k < 6; k++) {
        int f = tid + k * 256;          // f < 1536
        int c = f >> 2, li = (f & 3) * 4;
        float4 v = *(const float4*)&xb[(size_t)c * 1024 + n0 + li];
        xs[c][li] = v.x; xs[c][li + 1] = v.y; xs[c][li + 2] = v.z; xs[c][li + 3] = v.w;
    }
    __syncthreads();

    int l = tid >> 4, part = tid & 15;
    float s = 0.f, sq = 0.f;
    #pragma unroll
    for (int j = 0; j < 24; j++) {
        float v = xs[part + j * 16][l];
        s += v; sq += v * v;
    }
    #pragma unroll
    for (int off = 1; off <= 8; off <<= 1) {
        s  += __shfl_xor(s,  off);
        sq += __shfl_xor(sq, off);
    }
    float mu   = s * (1.0f / 384.0f);
    float rstd = rsqrtf(sq * (1.0f / 384.0f) - mu * mu + 1e-6f);

    unsigned short* tp = t + (size_t)(b * 1024 + n0 + l) * 384 + part * 24;
    unsigned o32[12];
    #pragma unroll
    for (int m = 0; m < 12; m++) {
        int c0 = part * 24 + m * 2;
        unsigned lo = f2bf((xs[c0][l]     - mu) * rstd * wgt[c0]     + bia[c0]);
        unsigned hi = f2bf((xs[c0 + 1][l] - mu) * rstd * wgt[c0 + 1] + bia[c0 + 1]);
        o32[m] = lo | (hi << 16);
    }
    #pragma unroll
    for (int m = 0; m < 3; m++) {
        int4 pk = { (int)o32[m * 4], (int)o32[m * 4 + 1], (int)o32[m * 4 + 2], (int)o32[m * 4 + 3] };
        *(int4*)&tp[m * 8] = pk;
    }
}

// ---------------------------------------------------------------------------
// Kernel 2: QKV GEMM, 64x128 tile, BK=64. Grid (128, 9) = 1152 blocks.
// LDS: ONE flat allocation, manually partitioned (As / Bs / Cs-overlay) —
// guarantees the 64x136 transpose buffer stays in-bounds (R10 bug fix).
// j-blocks: 0-2 -> q [b,n,384] (pre-scaled), 3-5 -> k, 6-8 -> v^T [b,h,d,n].
// ---------------------------------------------------------------------------
__global__ __launch_bounds__(256) void qkv_mfma(const unsigned short* __restrict__ t,
                                                const unsigned short* __restrict__ w,
                                                unsigned short* __restrict__ qn,
                                                unsigned short* __restrict__ kn,
                                                unsigned short* __restrict__ vt) {
    __shared__ __align__(16) unsigned short lds[64 * 72 + 128 * 72];  // 27648 B
    unsigned short (*As)[72]  = (unsigned short (*)[72])&lds[0];
    unsigned short (*Bs)[72]  = (unsigned short (*)[72])&lds[64 * 72];
    unsigned short (*Cs)[136] = (unsigned short (*)[136])&lds[0];     // 8704 <= 13824 shorts

    int tid = threadIdx.x;
    int m0 = blockIdx.x * 64;
    int jb = blockIdx.y;
    int j0 = jb * 128;
    int lane = tid & 63, wid = tid >> 6;
    int wr = wid >> 1, wc = wid & 1;
    int q16 = lane & 15, quad = lane >> 4;

    f32x4 acc[2][4] = {};

    const int srowA = tid >> 2, scA = (tid & 3) * 16;
    const int srowB = tid >> 1, scB = (tid & 1) * 32;
    for (int k0 = 0; k0 < 384; k0 += 64) {
        const unsigned short* ga = &t[(size_t)(m0 + srowA) * 384 + k0 + scA];
        const unsigned short* gb = &w[(size_t)(j0 + srowB) * 384 + k0 + scB];
        *(int4*)&As[srowA][scA]     = *(const int4*)(ga);
        *(int4*)&As[srowA][scA + 8] = *(const int4*)(ga + 8);
        *(int4*)&Bs[srowB][scB]      = *(const int4*)(gb);
        *(int4*)&Bs[srowB][scB + 8]  = *(const int4*)(gb + 8);
        *(int4*)&Bs[srowB][scB + 16] = *(const int4*)(gb + 16);
        *(int4*)&Bs[srowB][scB + 24] = *(const int4*)(gb + 24);
        __syncthreads();
        #pragma unroll
        for (int s = 0; s < 2; s++) {
            s16x8 af[2], bfr[4];
            #pragma unroll
            for (int mi = 0; mi < 2; mi++) af[mi]  = *(const s16x8*)&As[wr * 32 + mi * 16 + q16][s * 32 + quad * 8];
            #pragma unroll
            for (int ni = 0; ni < 4; ni++) bfr[ni] = *(const s16x8*)&Bs[wc * 64 + ni * 16 + q16][s * 32 + quad * 8];
            #pragma unroll
            for (int mi = 0; mi < 2; mi++)
                #pragma unroll
                for (int ni = 0; ni < 4; ni++)
                    acc[mi][ni] = __builtin_amdgcn_mfma_f32_16x16x32_bf16(af[mi], bfr[ni], acc[mi][ni], 0, 0, 0);
        }
        __syncthreads();
    }

    if (jb < 6) {
        // q/k: LDS-transpose epilogue (single pass), coalesced int4 stores
        const float sc = (jb < 3) ? SCALE_ : 1.0f;
        unsigned short* dst = (jb < 3) ? qn : kn;
        int coff = (jb < 3 ? jb : jb - 3) * 128;
        #pragma unroll
        for (int mi = 0; mi < 2; mi++)
            #pragma unroll
            for (int ni = 0; ni < 4; ni++)
                #pragma unroll
                for (int r = 0; r < 4; r++)
                    Cs[wr * 32 + mi * 16 + quad * 4 + r][wc * 64 + ni * 16 + q16] = f2bf(acc[mi][ni][r] * sc);
        __syncthreads();
        #pragma unroll
        for (int i = tid; i < 1024; i += 256) {
            int rr = i >> 4, cc = (i & 15) * 8;
            int m = m0 + rr;
            int bsel = m >> 10, nn = m & 1023;
            *(int4*)&dst[(size_t)(bsel * 1024 + nn) * 384 + coff + cc] = *(const int4*)&Cs[rr][cc];
        }
    } else {
        // v: direct ushort4 stores to [b,h,d,n]
        #pragma unroll
        for (int mi = 0; mi < 2; mi++) {
            int m_base = m0 + wr * 32 + mi * 16 + quad * 4;
            int bb = m_base >> 10;
            int nn = m_base & 1023;
            #pragma unroll
            for (int ni = 0; ni < 4; ni++) {
                int c2 = (jb - 6) * 128 + wc * 64 + ni * 16 + q16;
                int head = c2 / 48;
                int dd = c2 - head * 48;
                f32x4 a = acc[mi][ni];
                size_t base = (((size_t)bb * 8 + head) * 48 + dd) * 1024 + nn;
                ushort4 v4 = { f2bf(a.x), f2bf(a.y), f2bf(a.z), f2bf(a.w) };
                *(ushort4*)&vt[base] = v4;
            }
        }
    }
}

// ---------------------------------------------------------------------------
// Kernel 3: flash attention — q-tile 64, grid (16,8,8)=1024 blocks, 3/CU.
// Dbuf 64-key chunks, one sync/iter, exp(s-8) no-max (R8/R9-verified dataflow).
// ---------------------------------------------------------------------------
__global__ __launch_bounds__(256) void attn_mfma(const unsigned short* __restrict__ qn,
                                                 const unsigned short* __restrict__ kn,
                                                 const unsigned short* __restrict__ vt,
                                                 unsigned short* __restrict__ ao) {
    __shared__ __align__(16) unsigned short Ks[2][64][72];   // Ks[0] also Q pre-loop + epilogue
    __shared__ __align__(16) unsigned short Vt[2][48][72];
    __shared__ __align__(16) unsigned short Ps[4][16][72];

    int tid = threadIdx.x, lane = tid & 63, wid = tid >> 6;
    int q16 = lane & 15, quad = lane >> 4;
    int qt = blockIdx.x, h = blockIdx.y, b = blockIdx.z;
    const unsigned short* qp = qn + (size_t)b * 1024 * 384 + h * 48;
    const unsigned short* kp = kn + (size_t)b * 1024 * 384 + h * 48;
    const unsigned short* vp = vt + ((size_t)b * NH_ + h) * 48 * N_;

    int4 z4 = {0, 0, 0, 0};

    // stage Q (64 x 48) into Ks[0]; zero d-pad
    if (tid < 128) {
        int r = tid >> 1, off = (tid & 1) * 24;
        const unsigned short* gp = qp + (size_t)(qt * 64 + r) * 384 + off;
        *(int4*)&Ks[0][r][off]      = *(const int4*)gp;
        *(int4*)&Ks[0][r][off + 8]  = *(const int4*)(gp + 8);
        *(int4*)&Ks[0][r][off + 16] = *(const int4*)(gp + 16);
        if ((tid & 1) == 0) { *(int4*)&Ks[0][r][48] = z4; *(int4*)&Ks[0][r][56] = z4; }
    }
    __syncthreads();

    s16x8 qf0 = *(const s16x8*)&Ks[0][wid * 16 + q16][quad * 8];
    s16x8 qf1 = *(const s16x8*)&Ks[0][wid * 16 + q16][32 + quad * 8];
    __syncthreads();   // Q reads done before K staging overwrites

    // staging roles: tid<128 -> K row kr half koff; tid>=128 -> V 3x16B chunks
    const int kr = tid >> 1, koff = (tid & 1) * 24;
    const int vi = tid - 128;

    // prologue: chunk 0 into buffer 0
    if (tid < 128) {
        const unsigned short* gp = kp + (size_t)kr * 384 + koff;
        *(int4*)&Ks[0][kr][koff]      = *(const int4*)gp;
        *(int4*)&Ks[0][kr][koff + 8]  = *(const int4*)(gp + 8);
        *(int4*)&Ks[0][kr][koff + 16] = *(const int4*)(gp + 16);
        if ((tid & 1) == 0) { *(int4*)&Ks[0][kr][48] = z4; *(int4*)&Ks[0][kr][56] = z4; }
    } else {
        #pragma unroll
        for (int j = 0; j < 3; j++) {
            int c = vi + j * 128;
            int row = c >> 3, g8 = (c & 7) * 8;
            *(int4*)&Vt[0][row][g8] = *(const int4*)&vp[(size_t)row * 1024 + g8];
        }
    }
    __syncthreads();

    f32x4 o[3] = {};
    f32x4 lrv = {};

    for (int kt = 0; kt < 16; kt++) {
        int cur = kt & 1;

        // (1) prefetch kt+1 into registers
        int4 pf0, pf1, pf2;
        if (kt < 15) {
            if (tid < 128) {
                const unsigned short* gp = kp + (size_t)((kt + 1) * 64 + kr) * 384 + koff;
                pf0 = *(const int4*)gp;
                pf1 = *(const int4*)(gp + 8);
                pf2 = *(const int4*)(gp + 16);
            } else {
                pf0 = *(const int4*)&vp[(size_t)((vi +   0) >> 3) * 1024 + (kt + 1) * 64 + ((vi +   0) & 7) * 8];
                pf1 = *(const int4*)&vp[(size_t)((vi + 128) >> 3) * 1024 + (kt + 1) * 64 + ((vi + 128) & 7) * 8];
                pf2 = *(const int4*)&vp[(size_t)((vi + 256) >> 3) * 1024 + (kt + 1) * 64 + ((vi + 256) & 7) * 8];
            }
        }

        // (2) compute on buffer cur
        f32x4 s[4];
        #pragma unroll
        for (int nt = 0; nt < 4; nt++) {
            s16x8 k0 = *(const s16x8*)&Ks[cur][nt * 16 + q16][quad * 8];
            s16x8 k1 = *(const s16x8*)&Ks[cur][nt * 16 + q16][32 + quad * 8];
            f32x4 z = {};
            z = __builtin_amdgcn_mfma_f32_16x16x32_bf16(qf0, k0, z, 0, 0, 0);
            z = __builtin_amdgcn_mfma_f32_16x16x32_bf16(qf1, k1, z, 0, 0, 0);
            s[nt] = z;
        }

        #pragma unroll
        for (int nt = 0; nt < 4; nt++) {
            s[nt].x = __expf(s[nt].x - 8.0f);
            s[nt].y = __expf(s[nt].y - 8.0f);
            s[nt].z = __expf(s[nt].z - 8.0f);
            s[nt].w = __expf(s[nt].w - 8.0f);
            lrv += s[nt];
        }
        #pragma unroll
        for (int nt = 0; nt < 4; nt++)
            #pragma unroll
            for (int r = 0; r < 4; r++)
                Ps[wid][quad * 4 + r][nt * 16 + q16] = f2bf_trunc(s[nt][r]);
        #pragma unroll
        for (int c = 0; c < 2; c++) {
            s16x8 pfr = *(const s16x8*)&Ps[wid][q16][c * 32 + quad * 8];
            #pragma unroll
            for (int dt = 0; dt < 3; dt++) {
                s16x8 vf = *(const s16x8*)&Vt[cur][dt * 16 + q16][c * 32 + quad * 8];
                o[dt] = __builtin_amdgcn_mfma_f32_16x16x32_bf16(pfr, vf, o[dt], 0, 0, 0);
            }
        }

        // (3) write prefetch to buffer cur^1
        if (kt < 15) {
            int nb = cur ^ 1;
            if (tid < 128) {
                *(int4*)&Ks[nb][kr][koff]      = pf0;
                *(int4*)&Ks[nb][kr][koff + 8]  = pf1;
                *(int4*)&Ks[nb][kr][koff + 16] = pf2;
                if ((tid & 1) == 0) { *(int4*)&Ks[nb][kr][48] = z4; *(int4*)&Ks[nb][kr][56] = z4; }
            } else {
                *(int4*)&Vt[nb][(vi +   0) >> 3][((vi +   0) & 7) * 8] = pf0;
                *(int4*)&Vt[nb][(vi + 128) >> 3][((vi + 128) & 7) * 8] = pf1;
                *(int4*)&Vt[nb][(vi + 256) >> 3][((vi + 256) & 7) * 8] = pf2;
            }
        }
        // (4) one barrier per iteration
        __syncthreads();
    }

    // deferred row-sum over the 16 q16 lanes
    #pragma unroll
    for (int off = 1; off <= 8; off <<= 1) {
        lrv.x += __shfl_xor(lrv.x, off);
        lrv.y += __shfl_xor(lrv.y, off);
        lrv.z += __shfl_xor(lrv.z, off);
        lrv.w += __shfl_xor(lrv.w, off);
    }

    // epilogue: o/lrv -> Ks[0] (64 x 48) -> coalesced stores
    f32x4 inv;
    inv.x = __builtin_amdgcn_rcpf(lrv.x);
    inv.y = __builtin_amdgcn_rcpf(lrv.y);
    inv.z = __builtin_amdgcn_rcpf(lrv.z);
    inv.w = __builtin_amdgcn_rcpf(lrv.w);
    #pragma unroll
    for (int dt = 0; dt < 3; dt++)
        #pragma unroll
        for (int r = 0; r < 4; r++)
            Ks[0][wid * 16 + quad * 4 + r][dt * 16 + q16] = f2bf(o[dt][r] * inv[r]);
    __syncthreads();

    if (tid < 128) {
        int r = tid >> 1, off = (tid & 1) * 24;
        unsigned short* dst = ao + ((size_t)b * 1024 + qt * 64 + r) * 384 + h * 48 + off;
        *(int4*)dst        = *(const int4*)&Ks[0][r][off];
        *(int4*)(dst + 8)  = *(const int4*)&Ks[0][r][off + 8];
        *(int4*)(dst + 16) = *(const int4*)&Ks[0][r][off + 16];
    }
}

// ---------------------------------------------------------------------------
// Kernel 4: proj GEMM 64x128 tile, BK=64 + residual, transposed fp32 output.
// ---------------------------------------------------------------------------
__global__ __launch_bounds__(256) void proj_mfma(const unsigned short* __restrict__ ao,
                                                 const unsigned short* __restrict__ w,
                                                 const float* __restrict__ x,
                                                 float* __restrict__ out) {
    __shared__ __align__(16) unsigned short As[64][72];
    __shared__ __align__(16) unsigned short Bs[128][72];

    int tid = threadIdx.x;
    int m0 = blockIdx.x * 64;
    int j0 = blockIdx.y * 128;
    int lane = tid & 63, wid = tid >> 6;
    int wr = wid >> 1, wc = wid & 1;
    int q16 = lane & 15, quad = lane >> 4;

    f32x4 acc[2][4] = {};

    const int srowA = tid >> 2, scA = (tid & 3) * 16;
    const int srowB = tid >> 1, scB = (tid & 1) * 32;
    for (int k0 = 0; k0 < 384; k0 += 64) {
        const unsigned short* ga = &ao[(size_t)(m0 + srowA) * 384 + k0 + scA];
        const unsigned short* gb = &w[(size_t)(j0 + srowB) * 384 + k0 + scB];
        *(int4*)&As[srowA][scA]     = *(const int4*)(ga);
        *(int4*)&As[srowA][scA + 8] = *(const int4*)(ga + 8);
        *(int4*)&Bs[srowB][scB]      = *(const int4*)(gb);
        *(int4*)&Bs[srowB][scB + 8]  = *(const int4*)(gb + 8);
        *(int4*)&Bs[srowB][scB + 16] = *(const int4*)(gb + 16);
        *(int4*)&Bs[srowB][scB + 24] = *(const int4*)(gb + 24);
        __syncthreads();
        #pragma unroll
        for (int s = 0; s < 2; s++) {
            s16x8 af[2], bfr[4];
            #pragma unroll
            for (int mi = 0; mi < 2; mi++) af[mi]  = *(const s16x8*)&As[wr * 32 + mi * 16 + q16][s * 32 + quad * 8];
            #pragma unroll
            for (int ni = 0; ni < 4; ni++) bfr[ni] = *(const s16x8*)&Bs[wc * 64 + ni * 16 + q16][s * 32 + quad * 8];
            #pragma unroll
            for (int mi = 0; mi < 2; mi++)
                #pragma unroll
                for (int ni = 0; ni < 4; ni++)
                    acc[mi][ni] = __builtin_amdgcn_mfma_f32_16x16x32_bf16(af[mi], bfr[ni], acc[mi][ni], 0, 0, 0);
        }
        __syncthreads();
    }

    #pragma unroll
    for (int mi = 0; mi < 2; mi++) {
        int m_base = m0 + wr * 32 + mi * 16 + quad * 4;
        int bb = m_base >> 10;
        int nn = m_base & 1023;
        #pragma unroll
        for (int ni = 0; ni < 4; ni++) {
            int col = j0 + wc * 64 + ni * 16 + q16;
            size_t idx = ((size_t)bb * 384 + col) * 1024 + nn;
            float4 xr = *(const float4*)&x[idx];
            f32x4 a = acc[mi][ni];
            float4 ov = { xr.x + a.x, xr.y + a.y, xr.z + a.z, xr.w + a.w };
            *(float4*)&out[idx] = ov;
        }
    }
}

// ---------------------------------------------------------------------------
extern "C" void kernel_launch(void* const* d_in, const int* in_sizes, int n_in,
                              void* d_out, int out_size, void* d_ws, size_t ws_size,
                              hipStream_t stream) {
    const float* x     = (const float*)d_in[0];
    const float* wqkv  = (const float*)d_in[1];
    const float* wproj = (const float*)d_in[2];
    const float* lnw   = (const float*)d_in[3];
    const float* lnb   = (const float*)d_in[4];
    float* out = (float*)d_out;

    unsigned short* ws16 = (unsigned short*)d_ws;
    size_t off = 0;
    unsigned short* t_bf  = ws16 + off; off += (size_t)8192 * 384;
    unsigned short* wq_bf = ws16 + off; off += (size_t)1152 * 384;
    unsigned short* wp_bf = ws16 + off; off += (size_t)384 * 384;
    unsigned short* qn    = ws16 + off; off += (size_t)8192 * 384;   // [b,n,384] pre-scaled
    unsigned short* kn    = ws16 + off; off += (size_t)8192 * 384;   // [b,n,384]
    unsigned short* vt    = ws16 + off; off += (size_t)64 * 48 * 1024; // [b,h,d,n]
    unsigned short* ao_bf = ws16 + off; off += (size_t)8192 * 384;

    ln_cvt_kernel<<<512, 256, 0, stream>>>(x, lnw, lnb, wqkv, wproj, t_bf, wq_bf, wp_bf);
    qkv_mfma<<<dim3(128, 9), 256, 0, stream>>>(t_bf, wq_bf, qn, kn, vt);
    attn_mfma<<<dim3(16, NH_, B_), 256, 0, stream>>>(qn, kn, vt, ao_bf);
    proj_mfma<<<dim3(128, 3), 256, 0, stream>>>(ao_bf, wp_bf, x, out);
}

// Round 12
// 138.209 us; speedup vs baseline: 1.0633x; 1.0633x over previous
//
#include <hip/hip_runtime.h>
#include <math.h>

typedef __attribute__((ext_vector_type(4))) float f32x4;
typedef __attribute__((ext_vector_type(8))) short s16x8;

constexpr int B_ = 8, C_ = 384, N_ = 1024, NH_ = 8, D_ = 48;
constexpr float SCALE_ = 0.14433756729740643f; // 1/sqrt(48)

__device__ __forceinline__ unsigned short f2bf(float f) {
    unsigned u = __builtin_bit_cast(unsigned, f);
    u += 0x7fff + ((u >> 16) & 1);           // round-to-nearest-even
    return (unsigned short)(u >> 16);
}
__device__ __forceinline__ unsigned short f2bf_trunc(float f) {
    return (unsigned short)(__builtin_bit_cast(unsigned, f) >> 16);
}

// ---------------------------------------------------------------------------
// Kernel 1: LayerNorm (float4 loads, LDS transpose, int4 stores) + weight cvt.
// ---------------------------------------------------------------------------
__global__ __launch_bounds__(256) void ln_cvt_kernel(const float* __restrict__ x,
                                                     const float* __restrict__ lnw,
                                                     const float* __restrict__ lnb,
                                                     const float* __restrict__ wq,
                                                     const float* __restrict__ wp,
                                                     unsigned short* __restrict__ t,
                                                     unsigned short* __restrict__ wqb,
                                                     unsigned short* __restrict__ wpb) {
    int tid = threadIdx.x;
    int gid = blockIdx.x * 256 + tid;
    for (int i = gid; i < 1152 * 384; i += 512 * 256) wqb[i] = f2bf(wq[i]);
    for (int i = gid; i < 384 * 384;  i += 512 * 256) wpb[i] = f2bf(wp[i]);

    __shared__ float xs[384][17];
    __shared__ float wgt[384], bia[384];
    int b  = blockIdx.x >> 6;
    int n0 = (blockIdx.x & 63) << 4;
    for (int i = tid; i < 384; i += 256) { wgt[i] = lnw[i]; bia[i] = lnb[i]; }

    const float* xb = x + (size_t)b * 384 * 1024;
    #pragma unroll
    for (int k = 0; k < 6; k++) {
        int f = tid + k * 256;          // f < 1536
        int c = f >> 2, li = (f & 3) * 4;
        float4 v = *(const float4*)&xb[(size_t)c * 1024 + n0 + li];
        xs[c][li] = v.x; xs[c][li + 1] = v.y; xs[c][li + 2] = v.z; xs[c][li + 3] = v.w;
    }
    __syncthreads();

    int l = tid >> 4, part = tid & 15;
    float s = 0.f, sq = 0.f;
    #pragma unroll
    for (int j = 0; j < 24; j++) {
        float v = xs[part + j * 16][l];
        s += v; sq += v * v;
    }
    #pragma unroll
    for (int off = 1; off <= 8; off <<= 1) {
        s  += __shfl_xor(s,  off);
        sq += __shfl_xor(sq, off);
    }
    float mu   = s * (1.0f / 384.0f);
    float rstd = rsqrtf(sq * (1.0f / 384.0f) - mu * mu + 1e-6f);

    unsigned short* tp = t + (size_t)(b * 1024 + n0 + l) * 384 + part * 24;
    unsigned o32[12];
    #pragma unroll
    for (int m = 0; m < 12; m++) {
        int c0 = part * 24 + m * 2;
        unsigned lo = f2bf((xs[c0][l]     - mu) * rstd * wgt[c0]     + bia[c0]);
        unsigned hi = f2bf((xs[c0 + 1][l] - mu) * rstd * wgt[c0 + 1] + bia[c0 + 1]);
        o32[m] = lo | (hi << 16);
    }
    #pragma unroll
    for (int m = 0; m < 3; m++) {
        int4 pk = { (int)o32[m * 4], (int)o32[m * 4 + 1], (int)o32[m * 4 + 2], (int)o32[m * 4 + 3] };
        *(int4*)&tp[m * 8] = pk;
    }
}

// ---------------------------------------------------------------------------
// Kernel 2: QKV GEMM, 64x128 tile, BK=64. Grid (128, 9) = 1152 blocks.
// Flat LDS, manually partitioned (R11-verified).
// ---------------------------------------------------------------------------
__global__ __launch_bounds__(256) void qkv_mfma(const unsigned short* __restrict__ t,
                                                const unsigned short* __restrict__ w,
                                                unsigned short* __restrict__ qn,
                                                unsigned short* __restrict__ kn,
                                                unsigned short* __restrict__ vt) {
    __shared__ __align__(16) unsigned short lds[64 * 72 + 128 * 72];  // 27648 B
    unsigned short (*As)[72]  = (unsigned short (*)[72])&lds[0];
    unsigned short (*Bs)[72]  = (unsigned short (*)[72])&lds[64 * 72];
    unsigned short (*Cs)[136] = (unsigned short (*)[136])&lds[0];     // 8704 <= 13824 shorts

    int tid = threadIdx.x;
    int m0 = blockIdx.x * 64;
    int jb = blockIdx.y;
    int j0 = jb * 128;
    int lane = tid & 63, wid = tid >> 6;
    int wr = wid >> 1, wc = wid & 1;
    int q16 = lane & 15, quad = lane >> 4;

    f32x4 acc[2][4] = {};

    const int srowA = tid >> 2, scA = (tid & 3) * 16;
    const int srowB = tid >> 1, scB = (tid & 1) * 32;
    for (int k0 = 0; k0 < 384; k0 += 64) {
        const unsigned short* ga = &t[(size_t)(m0 + srowA) * 384 + k0 + scA];
        const unsigned short* gb = &w[(size_t)(j0 + srowB) * 384 + k0 + scB];
        *(int4*)&As[srowA][scA]     = *(const int4*)(ga);
        *(int4*)&As[srowA][scA + 8] = *(const int4*)(ga + 8);
        *(int4*)&Bs[srowB][scB]      = *(const int4*)(gb);
        *(int4*)&Bs[srowB][scB + 8]  = *(const int4*)(gb + 8);
        *(int4*)&Bs[srowB][scB + 16] = *(const int4*)(gb + 16);
        *(int4*)&Bs[srowB][scB + 24] = *(const int4*)(gb + 24);
        __syncthreads();
        #pragma unroll
        for (int s = 0; s < 2; s++) {
            s16x8 af[2], bfr[4];
            #pragma unroll
            for (int mi = 0; mi < 2; mi++) af[mi]  = *(const s16x8*)&As[wr * 32 + mi * 16 + q16][s * 32 + quad * 8];
            #pragma unroll
            for (int ni = 0; ni < 4; ni++) bfr[ni] = *(const s16x8*)&Bs[wc * 64 + ni * 16 + q16][s * 32 + quad * 8];
            #pragma unroll
            for (int mi = 0; mi < 2; mi++)
                #pragma unroll
                for (int ni = 0; ni < 4; ni++)
                    acc[mi][ni] = __builtin_amdgcn_mfma_f32_16x16x32_bf16(af[mi], bfr[ni], acc[mi][ni], 0, 0, 0);
        }
        __syncthreads();
    }

    if (jb < 6) {
        const float sc = (jb < 3) ? SCALE_ : 1.0f;
        unsigned short* dst = (jb < 3) ? qn : kn;
        int coff = (jb < 3 ? jb : jb - 3) * 128;
        #pragma unroll
        for (int mi = 0; mi < 2; mi++)
            #pragma unroll
            for (int ni = 0; ni < 4; ni++)
                #pragma unroll
                for (int r = 0; r < 4; r++)
                    Cs[wr * 32 + mi * 16 + quad * 4 + r][wc * 64 + ni * 16 + q16] = f2bf(acc[mi][ni][r] * sc);
        __syncthreads();
        #pragma unroll
        for (int i = tid; i < 1024; i += 256) {
            int rr = i >> 4, cc = (i & 15) * 8;
            int m = m0 + rr;
            int bsel = m >> 10, nn = m & 1023;
            *(int4*)&dst[(size_t)(bsel * 1024 + nn) * 384 + coff + cc] = *(const int4*)&Cs[rr][cc];
        }
    } else {
        #pragma unroll
        for (int mi = 0; mi < 2; mi++) {
            int m_base = m0 + wr * 32 + mi * 16 + quad * 4;
            int bb = m_base >> 10;
            int nn = m_base & 1023;
            #pragma unroll
            for (int ni = 0; ni < 4; ni++) {
                int c2 = (jb - 6) * 128 + wc * 64 + ni * 16 + q16;
                int head = c2 / 48;
                int dd = c2 - head * 48;
                f32x4 a = acc[mi][ni];
                size_t base = (((size_t)bb * 8 + head) * 48 + dd) * 1024 + nn;
                ushort4 v4 = { f2bf(a.x), f2bf(a.y), f2bf(a.z), f2bf(a.w) };
                *(ushort4*)&vt[base] = v4;
            }
        }
    }
}

// ---------------------------------------------------------------------------
// Kernel 3: flash attention (R9-verified): 128 q-rows, 4 waves x 2 groups of
// 16 q, dbuf 64-key chunks, one sync/iter, exp(s-8) no-max, deferred row-sum.
// Grid (8, NH, B) = 512 blocks.
// ---------------------------------------------------------------------------
__global__ __launch_bounds__(256) void attn_mfma(const unsigned short* __restrict__ qn,
                                                 const unsigned short* __restrict__ kn,
                                                 const unsigned short* __restrict__ vt,
                                                 unsigned short* __restrict__ ao) {
    __shared__ __align__(16) unsigned short Ks[2][64][72];   // also Q (128 rows flat) pre-loop + epilogue
    __shared__ __align__(16) unsigned short Vt[2][48][72];
    __shared__ __align__(16) unsigned short Ps[4][16][72];

    unsigned short (*Kflat)[72] = (unsigned short (*)[72])&Ks[0][0][0];  // 128 rows

    int tid = threadIdx.x, lane = tid & 63, wid = tid >> 6;
    int q16 = lane & 15, quad = lane >> 4;
    int qt = blockIdx.x, h = blockIdx.y, b = blockIdx.z;
    const unsigned short* qp = qn + (size_t)b * 1024 * 384 + h * 48;
    const unsigned short* kp = kn + (size_t)b * 1024 * 384 + h * 48;
    const unsigned short* vp = vt + ((size_t)b * NH_ + h) * 48 * N_;

    int4 z4 = {0, 0, 0, 0};

    // stage Q (128 x 48) into flat Ks; zero d-pad
    {
        int r = tid >> 1, off = (tid & 1) * 24;
        const unsigned short* gp = qp + (size_t)(qt * 128 + r) * 384 + off;
        *(int4*)&Kflat[r][off]      = *(const int4*)gp;
        *(int4*)&Kflat[r][off + 8]  = *(const int4*)(gp + 8);
        *(int4*)&Kflat[r][off + 16] = *(const int4*)(gp + 16);
        if ((tid & 1) == 0) { *(int4*)&Kflat[r][48] = z4; *(int4*)&Kflat[r][56] = z4; }
    }
    __syncthreads();

    s16x8 qf[2][2];
    #pragma unroll
    for (int g = 0; g < 2; g++) {
        qf[g][0] = *(const s16x8*)&Kflat[wid * 32 + g * 16 + q16][quad * 8];
        qf[g][1] = *(const s16x8*)&Kflat[wid * 32 + g * 16 + q16][32 + quad * 8];
    }
    __syncthreads();   // Q reads done before K staging overwrites

    // staging roles: tid<128 -> K (row=tid>>1, half=tid&1); tid>=128 -> V 3x16B
    const int kr = tid >> 1, koff = (tid & 1) * 24;
    const int vi = tid - 128;

    // prologue: chunk 0 into buffer 0
    {
        if (tid < 128) {
            const unsigned short* gp = kp + (size_t)kr * 384 + koff;
            *(int4*)&Ks[0][kr][koff]      = *(const int4*)gp;
            *(int4*)&Ks[0][kr][koff + 8]  = *(const int4*)(gp + 8);
            *(int4*)&Ks[0][kr][koff + 16] = *(const int4*)(gp + 16);
            if ((tid & 1) == 0) { *(int4*)&Ks[0][kr][48] = z4; *(int4*)&Ks[0][kr][56] = z4; }
        } else {
            #pragma unroll
            for (int j = 0; j < 3; j++) {
                int c = vi + j * 128;
                int row = c >> 3, g8 = (c & 7) * 8;
                *(int4*)&Vt[0][row][g8] = *(const int4*)&vp[(size_t)row * 1024 + g8];
            }
        }
    }
    __syncthreads();

    f32x4 o[2][3] = {};
    f32x4 lrv[2] = {};

    for (int kt = 0; kt < 16; kt++) {
        int cur = kt & 1;

        // (1) prefetch kt+1 into registers
        int4 pf0, pf1, pf2;
        if (kt < 15) {
            if (tid < 128) {
                const unsigned short* gp = kp + (size_t)((kt + 1) * 64 + kr) * 384 + koff;
                pf0 = *(const int4*)gp;
                pf1 = *(const int4*)(gp + 8);
                pf2 = *(const int4*)(gp + 16);
            } else {
                pf0 = *(const int4*)&vp[(size_t)((vi +   0) >> 3) * 1024 + (kt + 1) * 64 + ((vi +   0) & 7) * 8];
                pf1 = *(const int4*)&vp[(size_t)((vi + 128) >> 3) * 1024 + (kt + 1) * 64 + ((vi + 128) & 7) * 8];
                pf2 = *(const int4*)&vp[(size_t)((vi + 256) >> 3) * 1024 + (kt + 1) * 64 + ((vi + 256) & 7) * 8];
            }
        }

        // (2) compute on buffer cur
        f32x4 s[2][4];
        #pragma unroll
        for (int nt = 0; nt < 4; nt++) {
            s16x8 k0 = *(const s16x8*)&Ks[cur][nt * 16 + q16][quad * 8];
            s16x8 k1 = *(const s16x8*)&Ks[cur][nt * 16 + q16][32 + quad * 8];
            #pragma unroll
            for (int g = 0; g < 2; g++) {
                f32x4 z = {};
                z = __builtin_amdgcn_mfma_f32_16x16x32_bf16(qf[g][0], k0, z, 0, 0, 0);
                z = __builtin_amdgcn_mfma_f32_16x16x32_bf16(qf[g][1], k1, z, 0, 0, 0);
                s[g][nt] = z;
            }
        }

        #pragma unroll
        for (int g = 0; g < 2; g++) {
            #pragma unroll
            for (int nt = 0; nt < 4; nt++) {
                s[g][nt].x = __expf(s[g][nt].x - 8.0f);
                s[g][nt].y = __expf(s[g][nt].y - 8.0f);
                s[g][nt].z = __expf(s[g][nt].z - 8.0f);
                s[g][nt].w = __expf(s[g][nt].w - 8.0f);
                lrv[g] += s[g][nt];
            }
            #pragma unroll
            for (int nt = 0; nt < 4; nt++)
                #pragma unroll
                for (int r = 0; r < 4; r++)
                    Ps[wid][quad * 4 + r][nt * 16 + q16] = f2bf_trunc(s[g][nt][r]);
            #pragma unroll
            for (int c = 0; c < 2; c++) {
                s16x8 pfr = *(const s16x8*)&Ps[wid][q16][c * 32 + quad * 8];
                #pragma unroll
                for (int dt = 0; dt < 3; dt++) {
                    s16x8 vf = *(const s16x8*)&Vt[cur][dt * 16 + q16][c * 32 + quad * 8];
                    o[g][dt] = __builtin_amdgcn_mfma_f32_16x16x32_bf16(pfr, vf, o[g][dt], 0, 0, 0);
                }
            }
        }

        // (3) write prefetch to buffer cur^1
        if (kt < 15) {
            int nb = cur ^ 1;
            if (tid < 128) {
                *(int4*)&Ks[nb][kr][koff]      = pf0;
                *(int4*)&Ks[nb][kr][koff + 8]  = pf1;
                *(int4*)&Ks[nb][kr][koff + 16] = pf2;
                if ((tid & 1) == 0) { *(int4*)&Ks[nb][kr][48] = z4; *(int4*)&Ks[nb][kr][56] = z4; }
            } else {
                *(int4*)&Vt[nb][(vi +   0) >> 3][((vi +   0) & 7) * 8] = pf0;
                *(int4*)&Vt[nb][(vi + 128) >> 3][((vi + 128) & 7) * 8] = pf1;
                *(int4*)&Vt[nb][(vi + 256) >> 3][((vi + 256) & 7) * 8] = pf2;
            }
        }
        // (4) one barrier per iteration
        __syncthreads();
    }

    // deferred row-sum: butterfly over the 16 q16 lanes
    #pragma unroll
    for (int g = 0; g < 2; g++) {
        #pragma unroll
        for (int off = 1; off <= 8; off <<= 1) {
            lrv[g].x += __shfl_xor(lrv[g].x, off);
            lrv[g].y += __shfl_xor(lrv[g].y, off);
            lrv[g].z += __shfl_xor(lrv[g].z, off);
            lrv[g].w += __shfl_xor(lrv[g].w, off);
        }
    }

    // epilogue: o/lrow -> flat Ks (128 x 48) -> coalesced stores
    #pragma unroll
    for (int g = 0; g < 2; g++) {
        f32x4 inv;
        inv.x = __builtin_amdgcn_rcpf(lrv[g].x);
        inv.y = __builtin_amdgcn_rcpf(lrv[g].y);
        inv.z = __builtin_amdgcn_rcpf(lrv[g].z);
        inv.w = __builtin_amdgcn_rcpf(lrv[g].w);
        #pragma unroll
        for (int dt = 0; dt < 3; dt++)
            #pragma unroll
            for (int r = 0; r < 4; r++)
                Kflat[wid * 32 + g * 16 + quad * 4 + r][dt * 16 + q16] = f2bf(o[g][dt][r] * inv[r]);
    }
    __syncthreads();

    {
        int r = tid >> 1, off = (tid & 1) * 24;
        unsigned short* dst = ao + ((size_t)b * 1024 + qt * 128 + r) * 384 + h * 48 + off;
        *(int4*)dst        = *(const int4*)&Kflat[r][off];
        *(int4*)(dst + 8)  = *(const int4*)&Kflat[r][off + 8];
        *(int4*)(dst + 16) = *(const int4*)&Kflat[r][off + 16];
    }
}

// ---------------------------------------------------------------------------
// Kernel 4: proj GEMM 64x64 tile, BK=64 + residual. Grid (128, 6) = 768 blocks.
// ---------------------------------------------------------------------------
__global__ __launch_bounds__(256) void proj_mfma(const unsigned short* __restrict__ ao,
                                                 const unsigned short* __restrict__ w,
                                                 const float* __restrict__ x,
                                                 float* __restrict__ out) {
    __shared__ __align__(16) unsigned short As[64][72];
    __shared__ __align__(16) unsigned short Bs[64][72];

    int tid = threadIdx.x;
    int m0 = blockIdx.x * 64;
    int j0 = blockIdx.y * 64;
    int lane = tid & 63, wid = tid >> 6;
    int wr = wid >> 1, wc = wid & 1;
    int q16 = lane & 15, quad = lane >> 4;

    f32x4 acc[2][2] = {};

    const int srow = tid >> 2, sc = (tid & 3) * 16;
    for (int k0 = 0; k0 < 384; k0 += 64) {
        const unsigned short* ga = &ao[(size_t)(m0 + srow) * 384 + k0 + sc];
        const unsigned short* gb = &w[(size_t)(j0 + srow) * 384 + k0 + sc];
        *(int4*)&As[srow][sc]     = *(const int4*)(ga);
        *(int4*)&As[srow][sc + 8] = *(const int4*)(ga + 8);
        *(int4*)&Bs[srow][sc]     = *(const int4*)(gb);
        *(int4*)&Bs[srow][sc + 8] = *(const int4*)(gb + 8);
        __syncthreads();
        #pragma unroll
        for (int s = 0; s < 2; s++) {
            s16x8 af[2], bfr[2];
            #pragma unroll
            for (int mi = 0; mi < 2; mi++) af[mi]  = *(const s16x8*)&As[wr * 32 + mi * 16 + q16][s * 32 + quad * 8];
            #pragma unroll
            for (int ni = 0; ni < 2; ni++) bfr[ni] = *(const s16x8*)&Bs[wc * 32 + ni * 16 + q16][s * 32 + quad * 8];
            #pragma unroll
            for (int mi = 0; mi < 2; mi++)
                #pragma unroll
                for (int ni = 0; ni < 2; ni++)
                    acc[mi][ni] = __builtin_amdgcn_mfma_f32_16x16x32_bf16(af[mi], bfr[ni], acc[mi][ni], 0, 0, 0);
        }
        __syncthreads();
    }

    #pragma unroll
    for (int mi = 0; mi < 2; mi++) {
        int m_base = m0 + wr * 32 + mi * 16 + quad * 4;
        int bb = m_base >> 10;
        int nn = m_base & 1023;
        #pragma unroll
        for (int ni = 0; ni < 2; ni++) {
            int col = j0 + wc * 32 + ni * 16 + q16;
            size_t idx = ((size_t)bb * 384 + col) * 1024 + nn;
            float4 xr = *(const float4*)&x[idx];
            f32x4 a = acc[mi][ni];
            float4 ov = { xr.x + a.x, xr.y + a.y, xr.z + a.z, xr.w + a.w };
            *(float4*)&out[idx] = ov;
        }
    }
}

// ---------------------------------------------------------------------------
extern "C" void kernel_launch(void* const* d_in, const int* in_sizes, int n_in,
                              void* d_out, int out_size, void* d_ws, size_t ws_size,
                              hipStream_t stream) {
    const float* x     = (const float*)d_in[0];
    const float* wqkv  = (const float*)d_in[1];
    const float* wproj = (const float*)d_in[2];
    const float* lnw   = (const float*)d_in[3];
    const float* lnb   = (const float*)d_in[4];
    float* out = (float*)d_out;

    unsigned short* ws16 = (unsigned short*)d_ws;
    size_t off = 0;
    unsigned short* t_bf  = ws16 + off; off += (size_t)8192 * 384;
    unsigned short* wq_bf = ws16 + off; off += (size_t)1152 * 384;
    unsigned short* wp_bf = ws16 + off; off += (size_t)384 * 384;
    unsigned short* qn    = ws16 + off; off += (size_t)8192 * 384;   // [b,n,384] pre-scaled
    unsigned short* kn    = ws16 + off; off += (size_t)8192 * 384;   // [b,n,384]
    unsigned short* vt    = ws16 + off; off += (size_t)64 * 48 * 1024; // [b,h,d,n]
    unsigned short* ao_bf = ws16 + off; off += (size_t)8192 * 384;

    ln_cvt_kernel<<<512, 256, 0, stream>>>(x, lnw, lnb, wqkv, wproj, t_bf, wq_bf, wp_bf);
    qkv_mfma<<<dim3(128, 9), 256, 0, stream>>>(t_bf, wq_bf, qn, kn, vt);
    attn_mfma<<<dim3(8, NH_, B_), 256, 0, stream>>>(qn, kn, vt, ao_bf);
    proj_mfma<<<dim3(128, 6), 256, 0, stream>>>(ao_bf, wp_bf, x, out);
}